// Round 9
// baseline (324.441 us; speedup 1.0000x reference)
//
#include <hip/hip_runtime.h>
#include <math.h>

#define BATCH 4
#define SEQ 2048
#define DM 1024
#define NTOK (BATCH * SEQ)                 // 8192
#define NE ((size_t)NTOK * DM)             // 8,388,608 elements
#define WN ((size_t)DM * DM)               // 1,048,576 elements

using s16x8 = __attribute__((ext_vector_type(8))) short;
using f32x4 = __attribute__((ext_vector_type(4))) float;

// ---- bf16 helpers (RNE) ----------------------------------------------------
__device__ __forceinline__ unsigned short f2bf(float f) {
    unsigned u = __builtin_bit_cast(unsigned, f);
    u += 0x7FFFu + ((u >> 16) & 1u);
    return (unsigned short)(u >> 16);
}
__device__ __forceinline__ float bf2f(unsigned short h) {
    unsigned u = ((unsigned)h) << 16;
    return __builtin_bit_cast(float, u);
}

__device__ __forceinline__ f32x4 MFMA(s16x8 a, s16x8 b, f32x4 c) {
    return __builtin_amdgcn_mfma_f32_16x16x32_bf16(a, b, c, 0, 0, 0);
}

#define AS1 __attribute__((address_space(1)))
#define AS3 __attribute__((address_space(3)))
__device__ __forceinline__ void gll16(const void* g, void* l) {
    __builtin_amdgcn_global_load_lds((const AS1 void*)g, (AS3 void*)l, 16, 0, 0);
}

// LDS tile layout: [128 rows][64 bf16], 8 granules(16B) per row,
// granule g of row r stored at position (g ^ (r&7))  -> bank-conflict-free reads.
__device__ __forceinline__ s16x8 lds_frag(const short* base, int row, int g) {
    return *(const s16x8*)(base + row * 64 + ((g ^ (row & 7)) << 3));
}

// Stage a [128][64] bf16 tile from global (row stride rs elements) into LDS.
__device__ __forceinline__ void stage_tile(const unsigned short* g0, size_t rs,
                                           short* lds, int tid) {
    int lane = tid & 63, w = tid >> 6;
    #pragma unroll
    for (int c = 0; c < 4; ++c) {
        int s = c * 256 + w * 64 + lane;     // 16B slot id; dest = base + lane*16
        int row = s >> 3, gg = s & 7;
        int graw = gg ^ (row & 7);
        gll16(g0 + (size_t)row * rs + graw * 8, lds + (size_t)s * 8);
    }
}

// ---------------------------------------------------------------------------
// split_x: x fp32 -> x_hi, x_lo bf16 (same layout)
// ---------------------------------------------------------------------------
__global__ __launch_bounds__(256) void split_x(const float* __restrict__ x,
                                               unsigned short* __restrict__ xh,
                                               unsigned short* __restrict__ xl) {
    size_t n4 = NE / 4;
    for (size_t i = (size_t)blockIdx.x * 256 + threadIdx.x; i < n4;
         i += (size_t)gridDim.x * 256) {
        float4 v = ((const float4*)x)[i];
        ushort4 h, l;
        h.x = f2bf(v.x); l.x = f2bf(v.x - bf2f(h.x));
        h.y = f2bf(v.y); l.y = f2bf(v.y - bf2f(h.y));
        h.z = f2bf(v.z); l.z = f2bf(v.z - bf2f(h.z));
        h.w = f2bf(v.w); l.w = f2bf(v.w - bf2f(h.w));
        ((ushort4*)xh)[i] = h;
        ((ushort4*)xl)[i] = l;
    }
}

// ---------------------------------------------------------------------------
// split_w: z=0 Wq nat hi/lo; z=1 Wk nat hi/lo; z=2 Wv transposed hi only.
// grid (16,16,3), block 256.
// ---------------------------------------------------------------------------
__global__ __launch_bounds__(256) void split_w(
    const float* __restrict__ Wq, const float* __restrict__ Wk,
    const float* __restrict__ Wv,
    unsigned short* __restrict__ Wqh, unsigned short* __restrict__ Wql,
    unsigned short* __restrict__ Wkh, unsigned short* __restrict__ Wkl,
    unsigned short* __restrict__ Wvt) {
    const int z = blockIdx.z;
    const int tid = threadIdx.x;
    if (z < 2) {
        const float* W = z ? Wk : Wq;
        unsigned short* oh = z ? Wkh : Wqh;
        unsigned short* ol = z ? Wkl : Wql;
        size_t n4 = WN / 4;
        size_t stride = (size_t)gridDim.x * gridDim.y * 256;
        for (size_t i = ((size_t)blockIdx.y * gridDim.x + blockIdx.x) * 256 + tid;
             i < n4; i += stride) {
            float4 v = ((const float4*)W)[i];
            ushort4 h, l;
            h.x = f2bf(v.x); l.x = f2bf(v.x - bf2f(h.x));
            h.y = f2bf(v.y); l.y = f2bf(v.y - bf2f(h.y));
            h.z = f2bf(v.z); l.z = f2bf(v.z - bf2f(h.z));
            h.w = f2bf(v.w); l.w = f2bf(v.w - bf2f(h.w));
            ((ushort4*)oh)[i] = h;
            ((ushort4*)ol)[i] = l;
        }
    } else {
        // transpose 64x64 tile of Wv: Wvt[n][d] = Wv[d][n], hi only
        __shared__ float t[64][65];
        const int d0 = blockIdx.x * 64, n0 = blockIdx.y * 64;
        #pragma unroll
        for (int c = 0; c < 16; ++c) {
            int f = c * 256 + tid; int r = f >> 6, cc = f & 63;
            t[r][cc] = Wv[(size_t)(d0 + r) * DM + n0 + cc];
        }
        __syncthreads();
        #pragma unroll
        for (int c = 0; c < 16; ++c) {
            int f = c * 256 + tid; int r = f >> 6, cc = f & 63;
            Wvt[(size_t)(n0 + r) * DM + d0 + cc] = f2bf(t[cc][r]);
        }
    }
}

// ---------------------------------------------------------------------------
// gemm3_split: C[m][n] = sum_k A[m,k]*B[n,k], 3-term hi/lo MFMA, K=DM,
// A/B row stride DM, C (split hi/lo) row stride DM.
// Used for: M' = Wk.Wq^T  (grid 8x8)  and  Y = x.M'^T (grid 64x8).
// ---------------------------------------------------------------------------
__global__ __launch_bounds__(256, 2) void gemm3_split(
    const unsigned short* __restrict__ Ah_, const unsigned short* __restrict__ Al_,
    const unsigned short* __restrict__ Bh_, const unsigned short* __restrict__ Bl_,
    unsigned short* __restrict__ Ch, unsigned short* __restrict__ Cl) {
    const int m0 = blockIdx.x * 128, n0 = blockIdx.y * 128;
    __shared__ short Ah[128 * 64], Al[128 * 64], Bh[128 * 64], Bl[128 * 64];
    const int tid = threadIdx.x, lane = tid & 63, w = tid >> 6;
    const int wr = w >> 1, wc = w & 1;

    f32x4 acc[4][4];
    #pragma unroll
    for (int i = 0; i < 4; ++i)
        #pragma unroll
        for (int j = 0; j < 4; ++j) acc[i][j] = (f32x4){0.f, 0.f, 0.f, 0.f};

    for (int k0 = 0; k0 < DM; k0 += 64) {
        stage_tile(Ah_ + (size_t)m0 * DM + k0, DM, Ah, tid);
        stage_tile(Al_ + (size_t)m0 * DM + k0, DM, Al, tid);
        stage_tile(Bh_ + (size_t)n0 * DM + k0, DM, Bh, tid);
        stage_tile(Bl_ + (size_t)n0 * DM + k0, DM, Bl, tid);
        __syncthreads();
        #pragma unroll
        for (int ks = 0; ks < 2; ++ks) {
            const int g = ks * 4 + (lane >> 4);
            s16x8 a_h[4], a_l[4], b_h[4], b_l[4];
            #pragma unroll
            for (int mi = 0; mi < 4; ++mi) {
                int r = wr * 64 + mi * 16 + (lane & 15);
                a_h[mi] = lds_frag(Ah, r, g);
                a_l[mi] = lds_frag(Al, r, g);
            }
            #pragma unroll
            for (int ni = 0; ni < 4; ++ni) {
                int r = wc * 64 + ni * 16 + (lane & 15);
                b_h[ni] = lds_frag(Bh, r, g);
                b_l[ni] = lds_frag(Bl, r, g);
            }
            #pragma unroll
            for (int mi = 0; mi < 4; ++mi)
                #pragma unroll
                for (int ni = 0; ni < 4; ++ni) {
                    acc[mi][ni] = MFMA(a_h[mi], b_h[ni], acc[mi][ni]);
                    acc[mi][ni] = MFMA(a_h[mi], b_l[ni], acc[mi][ni]);
                    acc[mi][ni] = MFMA(a_l[mi], b_h[ni], acc[mi][ni]);
                }
        }
        __syncthreads();
    }
    #pragma unroll
    for (int mi = 0; mi < 4; ++mi)
        #pragma unroll
        for (int ni = 0; ni < 4; ++ni)
            #pragma unroll
            for (int r = 0; r < 4; ++r) {
                int row = m0 + wr * 64 + mi * 16 + (lane >> 4) * 4 + r;
                int col = n0 + wc * 64 + ni * 16 + (lane & 15);
                float v = acc[mi][ni][r];
                unsigned short h = f2bf(v);
                size_t o = (size_t)row * DM + col;
                Ch[o] = h;
                Cl[o] = f2bf(v - bf2f(h));
            }
}

// ---------------------------------------------------------------------------
// vt_mfma: Vt[n][tok] = Wvt(hi) . x(hi)^T, 1-term.  grid (8, 64).
// ---------------------------------------------------------------------------
__global__ __launch_bounds__(256, 2) void vt_mfma(
    const unsigned short* __restrict__ Wvt, const unsigned short* __restrict__ xh,
    unsigned short* __restrict__ Vt) {
    const int m0 = blockIdx.x * 128;            // over n-dim (1024)
    const int n0 = blockIdx.y * 128;            // over seq (8192)
    __shared__ short Ah[128 * 64], Bh[128 * 64];
    const int tid = threadIdx.x, lane = tid & 63, w = tid >> 6;
    const int wr = w >> 1, wc = w & 1;

    f32x4 acc[4][4];
    #pragma unroll
    for (int i = 0; i < 4; ++i)
        #pragma unroll
        for (int j = 0; j < 4; ++j) acc[i][j] = (f32x4){0.f, 0.f, 0.f, 0.f};

    for (int k0 = 0; k0 < DM; k0 += 64) {
        stage_tile(Wvt + (size_t)m0 * DM + k0, DM, Ah, tid);
        stage_tile(xh + (size_t)n0 * DM + k0, DM, Bh, tid);
        __syncthreads();
        #pragma unroll
        for (int ks = 0; ks < 2; ++ks) {
            const int g = ks * 4 + (lane >> 4);
            s16x8 a_h[4], b_h[4];
            #pragma unroll
            for (int mi = 0; mi < 4; ++mi)
                a_h[mi] = lds_frag(Ah, wr * 64 + mi * 16 + (lane & 15), g);
            #pragma unroll
            for (int ni = 0; ni < 4; ++ni)
                b_h[ni] = lds_frag(Bh, wc * 64 + ni * 16 + (lane & 15), g);
            #pragma unroll
            for (int mi = 0; mi < 4; ++mi)
                #pragma unroll
                for (int ni = 0; ni < 4; ++ni)
                    acc[mi][ni] = MFMA(a_h[mi], b_h[ni], acc[mi][ni]);
        }
        __syncthreads();
    }
    #pragma unroll
    for (int mi = 0; mi < 4; ++mi)
        #pragma unroll
        for (int ni = 0; ni < 4; ++ni)
            #pragma unroll
            for (int r = 0; r < 4; ++r) {
                int row = m0 + wr * 64 + mi * 16 + (lane >> 4) * 4 + r;
                int col = n0 + wc * 64 + ni * 16 + (lane & 15);
                Vt[(size_t)row * NTOK + col] = f2bf(acc[mi][ni][r]);
            }
}

// ---------------------------------------------------------------------------
// scores_mfma: P = mask(Y.x^T)/32, fp32 out.  3-term split.
// grid (16 jt, 16 t, 4 b), early-exit jt > t+1.
// ---------------------------------------------------------------------------
__global__ __launch_bounds__(256, 2) void scores_mfma(
    const unsigned short* __restrict__ Yh, const unsigned short* __restrict__ Yl,
    const unsigned short* __restrict__ xh, const unsigned short* __restrict__ xl,
    float* __restrict__ P) {
    const int jt = blockIdx.x, t = blockIdx.y, b = blockIdx.z;
    if (jt > t + 1) return;
    const int m0 = t * 128, n0 = jt * 128;
    const size_t qrow0 = (size_t)b * SEQ + m0;
    const size_t krow0 = (size_t)b * SEQ + n0;

    __shared__ short Ah[128 * 64], Al[128 * 64], Bh[128 * 64], Bl[128 * 64];
    const int tid = threadIdx.x, lane = tid & 63, w = tid >> 6;
    const int wr = w >> 1, wc = w & 1;

    f32x4 acc[4][4];
    #pragma unroll
    for (int i = 0; i < 4; ++i)
        #pragma unroll
        for (int j = 0; j < 4; ++j) acc[i][j] = (f32x4){0.f, 0.f, 0.f, 0.f};

    for (int k0 = 0; k0 < DM; k0 += 64) {
        stage_tile(Yh + qrow0 * DM + k0, DM, Ah, tid);
        stage_tile(Yl + qrow0 * DM + k0, DM, Al, tid);
        stage_tile(xh + krow0 * DM + k0, DM, Bh, tid);
        stage_tile(xl + krow0 * DM + k0, DM, Bl, tid);
        __syncthreads();
        #pragma unroll
        for (int ks = 0; ks < 2; ++ks) {
            const int g = ks * 4 + (lane >> 4);
            s16x8 a_h[4], a_l[4], b_h[4], b_l[4];
            #pragma unroll
            for (int mi = 0; mi < 4; ++mi) {
                int r = wr * 64 + mi * 16 + (lane & 15);
                a_h[mi] = lds_frag(Ah, r, g);
                a_l[mi] = lds_frag(Al, r, g);
            }
            #pragma unroll
            for (int ni = 0; ni < 4; ++ni) {
                int r = wc * 64 + ni * 16 + (lane & 15);
                b_h[ni] = lds_frag(Bh, r, g);
                b_l[ni] = lds_frag(Bl, r, g);
            }
            #pragma unroll
            for (int mi = 0; mi < 4; ++mi)
                #pragma unroll
                for (int ni = 0; ni < 4; ++ni) {
                    acc[mi][ni] = MFMA(a_h[mi], b_h[ni], acc[mi][ni]);
                    acc[mi][ni] = MFMA(a_h[mi], b_l[ni], acc[mi][ni]);
                    acc[mi][ni] = MFMA(a_l[mi], b_h[ni], acc[mi][ni]);
                }
        }
        __syncthreads();
    }
    const float scale = 1.0f / 32.0f;
    #pragma unroll
    for (int mi = 0; mi < 4; ++mi)
        #pragma unroll
        for (int ni = 0; ni < 4; ++ni)
            #pragma unroll
            for (int r = 0; r < 4; ++r) {
                int i = m0 + wr * 64 + mi * 16 + (lane >> 4) * 4 + r;  // within batch
                int j = n0 + wc * 64 + ni * 16 + (lane & 15);
                float v = (j <= i + 1) ? acc[mi][ni][r] * scale : -INFINITY;
                P[((size_t)b * SEQ + i) * SEQ + j] = v;
            }
}

// ---------------------------------------------------------------------------
// softmax_bf16: single-pass row softmax, fp32 logits in -> normalized bf16 out.
// ---------------------------------------------------------------------------
__global__ __launch_bounds__(256) void softmax_bf16(
    const float* __restrict__ P, unsigned short* __restrict__ P2) {
    const int row = blockIdx.x;
    const int b = row >> 11, i = row & (SEQ - 1);
    const int t = i >> 7;
    const int L = min(SEQ, (t + 2) * 128);
    const float* p = P + ((size_t)b * SEQ + i) * SEQ;
    unsigned short* q = P2 + ((size_t)b * SEQ + i) * SEQ;
    const int tid = threadIdx.x;
    __shared__ float red[4];

    float v[8];
    #pragma unroll
    for (int c = 0; c < 8; ++c) {
        int j = c * 256 + tid;
        v[c] = (j < L) ? p[j] : -INFINITY;
    }
    float m = -INFINITY;
    #pragma unroll
    for (int c = 0; c < 8; ++c) m = fmaxf(m, v[c]);
    #pragma unroll
    for (int o = 32; o > 0; o >>= 1) m = fmaxf(m, __shfl_xor(m, o));
    if ((tid & 63) == 0) red[tid >> 6] = m;
    __syncthreads();
    m = fmaxf(fmaxf(red[0], red[1]), fmaxf(red[2], red[3]));
    __syncthreads();

    float s = 0.f;
    #pragma unroll
    for (int c = 0; c < 8; ++c) { v[c] = __expf(v[c] - m); s += v[c]; }
    #pragma unroll
    for (int o = 32; o > 0; o >>= 1) s += __shfl_xor(s, o);
    if ((tid & 63) == 0) red[tid >> 6] = s;
    __syncthreads();
    s = red[0] + red[1] + red[2] + red[3];
    const float inv = 1.f / s;

    #pragma unroll
    for (int c = 0; c < 8; ++c) {
        int j = c * 256 + tid;
        if (j < L) q[j] = f2bf(v[c] * inv);
    }
}

// ---------------------------------------------------------------------------
// pv_mfma: Out = P2(bf16) @ V.  grid (8 n-tiles, 16 t, 4 b)
// ---------------------------------------------------------------------------
__global__ __launch_bounds__(256, 2) void pv_mfma(
    const unsigned short* __restrict__ P2, const unsigned short* __restrict__ Vt,
    float* __restrict__ Out) {
    const int bx = blockIdx.x, t = blockIdx.y, b = blockIdx.z;
    const int m0 = t * 128, n0 = bx * 128;
    const int jlim = min(SEQ, (t + 2) * 128);

    __shared__ short Pa[128 * 64], Vb[128 * 64];
    const int tid = threadIdx.x, lane = tid & 63, w = tid >> 6;
    const int wr = w >> 1, wc = w & 1;

    f32x4 acc[4][4];
    #pragma unroll
    for (int i = 0; i < 4; ++i)
        #pragma unroll
        for (int j = 0; j < 4; ++j) acc[i][j] = (f32x4){0.f, 0.f, 0.f, 0.f};

    for (int k0 = 0; k0 < jlim; k0 += 64) {
        stage_tile(P2 + ((size_t)b * SEQ + m0) * SEQ + k0, SEQ, Pa, tid);
        stage_tile(Vt + (size_t)n0 * NTOK + (size_t)b * SEQ + k0, NTOK, Vb, tid);
        __syncthreads();
        #pragma unroll
        for (int ks = 0; ks < 2; ++ks) {
            const int g = ks * 4 + (lane >> 4);
            s16x8 a_h[4], b_h[4];
            #pragma unroll
            for (int mi = 0; mi < 4; ++mi)
                a_h[mi] = lds_frag(Pa, wr * 64 + mi * 16 + (lane & 15), g);
            #pragma unroll
            for (int ni = 0; ni < 4; ++ni)
                b_h[ni] = lds_frag(Vb, wc * 64 + ni * 16 + (lane & 15), g);
            #pragma unroll
            for (int mi = 0; mi < 4; ++mi)
                #pragma unroll
                for (int ni = 0; ni < 4; ++ni)
                    acc[mi][ni] = MFMA(a_h[mi], b_h[ni], acc[mi][ni]);
        }
        __syncthreads();
    }
    #pragma unroll
    for (int mi = 0; mi < 4; ++mi)
        #pragma unroll
        for (int ni = 0; ni < 4; ++ni)
            #pragma unroll
            for (int r = 0; r < 4; ++r) {
                int i = m0 + wr * 64 + mi * 16 + (lane >> 4) * 4 + r;
                int col = n0 + wc * 64 + ni * 16 + (lane & 15);
                Out[((size_t)b * SEQ + i) * DM + col] = acc[mi][ni][r];
            }
}

// ---------------------------------------------------------------------------
extern "C" void kernel_launch(void* const* d_in, const int* in_sizes, int n_in,
                              void* d_out, int out_size, void* d_ws, size_t ws_size,
                              hipStream_t stream) {
    const float* x  = (const float*)d_in[0];
    const float* Wq = (const float*)d_in[1];
    const float* Wk = (const float*)d_in[2];
    const float* Wv = (const float*)d_in[3];

    // Workspace layout (bytes):
    //   [0   , 2NE)  : Vt bf16 [n=1024][tok=8192]          (live till pv)
    //   [2NE , 6NE)  : xh, xl bf16 (live till scores) -> P2 bf16 (softmax..pv)
    //   [6NE , 14NE) : P fp32; W-splits + M' + Wvt live inside BEFORE scores
    char* ws = (char*)d_ws;
    unsigned short* Vt = (unsigned short*)ws;               // NE elems
    unsigned short* xh = (unsigned short*)(ws + 2 * NE);    // NE
    unsigned short* xl = (unsigned short*)(ws + 4 * NE);    // NE
    float* P = (float*)(ws + 6 * NE);                       // 8*NE bytes
    unsigned short* P2 = (unsigned short*)(ws + 2 * NE);    // over xh/xl (4NE B)
    // scratch inside P's byte range (all dead before scores writes P):
    unsigned short* Wqh = (unsigned short*)(ws + 6 * NE);   // WN each
    unsigned short* Wql = Wqh + WN;
    unsigned short* Wkh = Wql + WN;
    unsigned short* Wkl = Wkh + WN;
    unsigned short* Mh  = Wkl + WN;    // M' = Wk.Wq^T hi
    unsigned short* Ml  = Mh + WN;     // M' lo
    unsigned short* Wvt = Ml + WN;     // Wv^T hi
    // Y splits use d_out as scratch (dead after scores; overwritten by Out):
    unsigned short* Yh = (unsigned short*)d_out;
    unsigned short* Yl = Yh + NE;

    split_x<<<2048, 256, 0, stream>>>(x, xh, xl);
    {
        dim3 g(16, 16, 3);
        split_w<<<g, 256, 0, stream>>>(Wq, Wk, Wv, Wqh, Wql, Wkh, Wkl, Wvt);
    }
    {   // M'[e][d] = sum_a Wk[e,a] Wq[d,a]
        dim3 g(8, 8);
        gemm3_split<<<g, 256, 0, stream>>>(Wkh, Wkl, Wqh, Wql, Mh, Ml);
    }
    {   // Y[i][e] = sum_d x[i,d] M'[e,d]
        dim3 g(NTOK / 128, DM / 128);
        gemm3_split<<<g, 256, 0, stream>>>(xh, xl, Mh, Ml, Yh, Yl);
    }
    {
        dim3 g(DM / 128, NTOK / 128);
        vt_mfma<<<g, 256, 0, stream>>>(Wvt, xh, Vt);
    }
    {
        dim3 g(16, 16, 4);
        scores_mfma<<<g, 256, 0, stream>>>(Yh, Yl, xh, xl, P);
    }
    softmax_bf16<<<BATCH * SEQ, 256, 0, stream>>>(P, P2);
    {
        dim3 g(DM / 128, 16, 4);
        pv_mfma<<<g, 256, 0, stream>>>(P2, Vt, (float*)d_out);
    }
}

// Round 12
// 297.220 us; speedup vs baseline: 1.0916x; 1.0916x over previous
//
#include <hip/hip_runtime.h>
#include <math.h>

#define BATCH 4
#define SEQ 2048
#define DM 1024
#define NTOK (BATCH * SEQ)                 // 8192
#define NE ((size_t)NTOK * DM)             // 8,388,608 elements
#define WN ((size_t)DM * DM)               // 1,048,576 elements

using s16x8 = __attribute__((ext_vector_type(8))) short;
using f32x4 = __attribute__((ext_vector_type(4))) float;

// ---- bf16 helpers (RNE) ----------------------------------------------------
__device__ __forceinline__ unsigned short f2bf(float f) {
    unsigned u = __builtin_bit_cast(unsigned, f);
    u += 0x7FFFu + ((u >> 16) & 1u);
    return (unsigned short)(u >> 16);
}
__device__ __forceinline__ float bf2f(unsigned short h) {
    unsigned u = ((unsigned)h) << 16;
    return __builtin_bit_cast(float, u);
}

__device__ __forceinline__ f32x4 MFMA(s16x8 a, s16x8 b, f32x4 c) {
    return __builtin_amdgcn_mfma_f32_16x16x32_bf16(a, b, c, 0, 0, 0);
}

#define AS1 __attribute__((address_space(1)))
#define AS3 __attribute__((address_space(3)))
__device__ __forceinline__ void gll16(const void* g, void* l) {
    __builtin_amdgcn_global_load_lds((const AS1 void*)g, (AS3 void*)l, 16, 0, 0);
}

// LDS tile layout: [128 rows][64 bf16], 8 granules(16B) per row,
// granule g of row r stored at position (g ^ (r&7))  -> bank-conflict-free reads.
__device__ __forceinline__ s16x8 lds_frag(const short* base, int row, int g) {
    return *(const s16x8*)(base + row * 64 + ((g ^ (row & 7)) << 3));
}

// Stage a [128][64] bf16 tile from global (row stride rs elements) into LDS.
__device__ __forceinline__ void stage_tile(const unsigned short* g0, size_t rs,
                                           short* lds, int tid) {
    int lane = tid & 63, w = tid >> 6;
    #pragma unroll
    for (int c = 0; c < 4; ++c) {
        int s = c * 256 + w * 64 + lane;     // 16B slot id; dest = base + lane*16
        int row = s >> 3, gg = s & 7;
        int graw = gg ^ (row & 7);
        gll16(g0 + (size_t)row * rs + graw * 8, lds + (size_t)s * 8);
    }
}

// ---------------------------------------------------------------------------
// split_x: x fp32 -> x_hi, x_lo bf16 (same layout)
// ---------------------------------------------------------------------------
__global__ __launch_bounds__(256) void split_x(const float* __restrict__ x,
                                               unsigned short* __restrict__ xh,
                                               unsigned short* __restrict__ xl) {
    size_t n4 = NE / 4;
    for (size_t i = (size_t)blockIdx.x * 256 + threadIdx.x; i < n4;
         i += (size_t)gridDim.x * 256) {
        float4 v = ((const float4*)x)[i];
        ushort4 h, l;
        h.x = f2bf(v.x); l.x = f2bf(v.x - bf2f(h.x));
        h.y = f2bf(v.y); l.y = f2bf(v.y - bf2f(h.y));
        h.z = f2bf(v.z); l.z = f2bf(v.z - bf2f(h.z));
        h.w = f2bf(v.w); l.w = f2bf(v.w - bf2f(h.w));
        ((ushort4*)xh)[i] = h;
        ((ushort4*)xl)[i] = l;
    }
}

// ---------------------------------------------------------------------------
// split_w: z=0 Wq nat hi/lo; z=1 Wk nat hi/lo; z=2 Wv transposed hi only.
// ---------------------------------------------------------------------------
__global__ __launch_bounds__(256) void split_w(
    const float* __restrict__ Wq, const float* __restrict__ Wk,
    const float* __restrict__ Wv,
    unsigned short* __restrict__ Wqh, unsigned short* __restrict__ Wql,
    unsigned short* __restrict__ Wkh, unsigned short* __restrict__ Wkl,
    unsigned short* __restrict__ Wvt) {
    const int z = blockIdx.z;
    const int tid = threadIdx.x;
    if (z < 2) {
        const float* W = z ? Wk : Wq;
        unsigned short* oh = z ? Wkh : Wqh;
        unsigned short* ol = z ? Wkl : Wql;
        size_t n4 = WN / 4;
        size_t stride = (size_t)gridDim.x * gridDim.y * 256;
        for (size_t i = ((size_t)blockIdx.y * gridDim.x + blockIdx.x) * 256 + tid;
             i < n4; i += stride) {
            float4 v = ((const float4*)W)[i];
            ushort4 h, l;
            h.x = f2bf(v.x); l.x = f2bf(v.x - bf2f(h.x));
            h.y = f2bf(v.y); l.y = f2bf(v.y - bf2f(h.y));
            h.z = f2bf(v.z); l.z = f2bf(v.z - bf2f(h.z));
            h.w = f2bf(v.w); l.w = f2bf(v.w - bf2f(h.w));
            ((ushort4*)oh)[i] = h;
            ((ushort4*)ol)[i] = l;
        }
    } else {
        __shared__ float t[64][65];
        const int d0 = blockIdx.x * 64, n0 = blockIdx.y * 64;
        #pragma unroll
        for (int c = 0; c < 16; ++c) {
            int f = c * 256 + tid; int r = f >> 6, cc = f & 63;
            t[r][cc] = Wv[(size_t)(d0 + r) * DM + n0 + cc];
        }
        __syncthreads();
        #pragma unroll
        for (int c = 0; c < 16; ++c) {
            int f = c * 256 + tid; int r = f >> 6, cc = f & 63;
            Wvt[(size_t)(n0 + r) * DM + d0 + cc] = f2bf(t[cc][r]);
        }
    }
}

// ---------------------------------------------------------------------------
// mvt_fused: flat 1024 blocks.
//  bid < 512 : M' split-K.  kz=bid>>6; m0/n0 from low bits.  3-term MFMA over
//              K slice [kz*128, +128), fp32 slab out (deterministic reduce later)
//  bid >= 512: vt tile.  Vt[n][tok] = Wvt(hi) . x(hi)^T, 1-term.
// ---------------------------------------------------------------------------
__global__ __launch_bounds__(256, 2) void mvt_fused(
    const unsigned short* __restrict__ Wkh_, const unsigned short* __restrict__ Wkl_,
    const unsigned short* __restrict__ Wqh_, const unsigned short* __restrict__ Wql_,
    float* __restrict__ Mslab,
    const unsigned short* __restrict__ Wvt_, const unsigned short* __restrict__ xh_,
    unsigned short* __restrict__ Vt) {
    __shared__ short L[4 * 128 * 64];
    short* Ah = L;            short* Al = L + 128 * 64;
    short* Bh = L + 2 * 128 * 64; short* Bl = L + 3 * 128 * 64;
    const int tid = threadIdx.x, lane = tid & 63, w = tid >> 6;
    const int wr = w >> 1, wc = w & 1;
    const int bid = blockIdx.x;

    f32x4 acc[4][4];
    #pragma unroll
    for (int i = 0; i < 4; ++i)
        #pragma unroll
        for (int j = 0; j < 4; ++j) acc[i][j] = (f32x4){0.f, 0.f, 0.f, 0.f};

    if (bid < 512) {
        const int kz = bid >> 6, rem = bid & 63;
        const int m0 = (rem & 7) * 128, n0 = (rem >> 3) * 128;
        #pragma unroll
        for (int kk = 0; kk < 2; ++kk) {
            const int k0 = kz * 128 + kk * 64;
            stage_tile(Wkh_ + (size_t)m0 * DM + k0, DM, Ah, tid);
            stage_tile(Wkl_ + (size_t)m0 * DM + k0, DM, Al, tid);
            stage_tile(Wqh_ + (size_t)n0 * DM + k0, DM, Bh, tid);
            stage_tile(Wql_ + (size_t)n0 * DM + k0, DM, Bl, tid);
            __syncthreads();
            #pragma unroll
            for (int ks = 0; ks < 2; ++ks) {
                const int g = ks * 4 + (lane >> 4);
                s16x8 a_h[4], a_l[4], b_h[4], b_l[4];
                #pragma unroll
                for (int mi = 0; mi < 4; ++mi) {
                    int r = wr * 64 + mi * 16 + (lane & 15);
                    a_h[mi] = lds_frag(Ah, r, g);
                    a_l[mi] = lds_frag(Al, r, g);
                }
                #pragma unroll
                for (int ni = 0; ni < 4; ++ni) {
                    int r = wc * 64 + ni * 16 + (lane & 15);
                    b_h[ni] = lds_frag(Bh, r, g);
                    b_l[ni] = lds_frag(Bl, r, g);
                }
                #pragma unroll
                for (int mi = 0; mi < 4; ++mi)
                    #pragma unroll
                    for (int ni = 0; ni < 4; ++ni) {
                        acc[mi][ni] = MFMA(a_h[mi], b_h[ni], acc[mi][ni]);
                        acc[mi][ni] = MFMA(a_h[mi], b_l[ni], acc[mi][ni]);
                        acc[mi][ni] = MFMA(a_l[mi], b_h[ni], acc[mi][ni]);
                    }
            }
            __syncthreads();
        }
        float* out = Mslab + (size_t)kz * WN;
        #pragma unroll
        for (int mi = 0; mi < 4; ++mi)
            #pragma unroll
            for (int ni = 0; ni < 4; ++ni)
                #pragma unroll
                for (int r = 0; r < 4; ++r) {
                    int row = m0 + wr * 64 + mi * 16 + (lane >> 4) * 4 + r;
                    int col = n0 + wc * 64 + ni * 16 + (lane & 15);
                    out[(size_t)row * DM + col] = acc[mi][ni][r];
                }
    } else {
        const int id2 = bid - 512;
        const int m0 = (id2 & 7) * 128;      // over DM
        const int n0 = (id2 >> 3) * 128;     // over NTOK
        for (int k0 = 0; k0 < DM; k0 += 64) {
            stage_tile(Wvt_ + (size_t)m0 * DM + k0, DM, Ah, tid);
            stage_tile(xh_ + (size_t)n0 * DM + k0, DM, Bh, tid);
            __syncthreads();
            #pragma unroll
            for (int ks = 0; ks < 2; ++ks) {
                const int g = ks * 4 + (lane >> 4);
                s16x8 a_h[4], b_h[4];
                #pragma unroll
                for (int mi = 0; mi < 4; ++mi)
                    a_h[mi] = lds_frag(Ah, wr * 64 + mi * 16 + (lane & 15), g);
                #pragma unroll
                for (int ni = 0; ni < 4; ++ni)
                    b_h[ni] = lds_frag(Bh, wc * 64 + ni * 16 + (lane & 15), g);
                #pragma unroll
                for (int mi = 0; mi < 4; ++mi)
                    #pragma unroll
                    for (int ni = 0; ni < 4; ++ni)
                        acc[mi][ni] = MFMA(a_h[mi], b_h[ni], acc[mi][ni]);
            }
            __syncthreads();
        }
        #pragma unroll
        for (int mi = 0; mi < 4; ++mi)
            #pragma unroll
            for (int ni = 0; ni < 4; ++ni)
                #pragma unroll
                for (int r = 0; r < 4; ++r) {
                    int row = m0 + wr * 64 + mi * 16 + (lane >> 4) * 4 + r;
                    int col = n0 + wc * 64 + ni * 16 + (lane & 15);
                    Vt[(size_t)row * NTOK + col] = f2bf(acc[mi][ni][r]);
                }
    }
}

// ---------------------------------------------------------------------------
// mreduce: sum 8 fp32 slabs -> M' hi/lo bf16.  grid 1024 x 256 (= WN/4 float4s).
// ---------------------------------------------------------------------------
__global__ __launch_bounds__(256) void mreduce(
    const float* __restrict__ Mslab,
    unsigned short* __restrict__ Mh, unsigned short* __restrict__ Ml) {
    size_t i = (size_t)blockIdx.x * 256 + threadIdx.x;   // float4 index, < WN/4
    float4 s = ((const float4*)Mslab)[i];
    #pragma unroll
    for (int r = 1; r < 8; ++r) {
        float4 v = ((const float4*)(Mslab + (size_t)r * WN))[i];
        s.x += v.x; s.y += v.y; s.z += v.z; s.w += v.w;
    }
    ushort4 h, l;
    h.x = f2bf(s.x); l.x = f2bf(s.x - bf2f(h.x));
    h.y = f2bf(s.y); l.y = f2bf(s.y - bf2f(h.y));
    h.z = f2bf(s.z); l.z = f2bf(s.z - bf2f(h.z));
    h.w = f2bf(s.w); l.w = f2bf(s.w - bf2f(h.w));
    ((ushort4*)Mh)[i] = h;
    ((ushort4*)Ml)[i] = l;
}

// ---------------------------------------------------------------------------
// gemm3_split: C[m][n] = sum_k A[m,k]*B[n,k], 3-term hi/lo MFMA, K=DM.
// Used for Y = x.M'^T (grid 64x8).
// ---------------------------------------------------------------------------
__global__ __launch_bounds__(256, 2) void gemm3_split(
    const unsigned short* __restrict__ Ah_, const unsigned short* __restrict__ Al_,
    const unsigned short* __restrict__ Bh_, const unsigned short* __restrict__ Bl_,
    unsigned short* __restrict__ Ch, unsigned short* __restrict__ Cl) {
    const int m0 = blockIdx.x * 128, n0 = blockIdx.y * 128;
    __shared__ short Ah[128 * 64], Al[128 * 64], Bh[128 * 64], Bl[128 * 64];
    const int tid = threadIdx.x, lane = tid & 63, w = tid >> 6;
    const int wr = w >> 1, wc = w & 1;

    f32x4 acc[4][4];
    #pragma unroll
    for (int i = 0; i < 4; ++i)
        #pragma unroll
        for (int j = 0; j < 4; ++j) acc[i][j] = (f32x4){0.f, 0.f, 0.f, 0.f};

    for (int k0 = 0; k0 < DM; k0 += 64) {
        stage_tile(Ah_ + (size_t)m0 * DM + k0, DM, Ah, tid);
        stage_tile(Al_ + (size_t)m0 * DM + k0, DM, Al, tid);
        stage_tile(Bh_ + (size_t)n0 * DM + k0, DM, Bh, tid);
        stage_tile(Bl_ + (size_t)n0 * DM + k0, DM, Bl, tid);
        __syncthreads();
        #pragma unroll
        for (int ks = 0; ks < 2; ++ks) {
            const int g = ks * 4 + (lane >> 4);
            s16x8 a_h[4], a_l[4], b_h[4], b_l[4];
            #pragma unroll
            for (int mi = 0; mi < 4; ++mi) {
                int r = wr * 64 + mi * 16 + (lane & 15);
                a_h[mi] = lds_frag(Ah, r, g);
                a_l[mi] = lds_frag(Al, r, g);
            }
            #pragma unroll
            for (int ni = 0; ni < 4; ++ni) {
                int r = wc * 64 + ni * 16 + (lane & 15);
                b_h[ni] = lds_frag(Bh, r, g);
                b_l[ni] = lds_frag(Bl, r, g);
            }
            #pragma unroll
            for (int mi = 0; mi < 4; ++mi)
                #pragma unroll
                for (int ni = 0; ni < 4; ++ni) {
                    acc[mi][ni] = MFMA(a_h[mi], b_h[ni], acc[mi][ni]);
                    acc[mi][ni] = MFMA(a_h[mi], b_l[ni], acc[mi][ni]);
                    acc[mi][ni] = MFMA(a_l[mi], b_h[ni], acc[mi][ni]);
                }
        }
        __syncthreads();
    }
    #pragma unroll
    for (int mi = 0; mi < 4; ++mi)
        #pragma unroll
        for (int ni = 0; ni < 4; ++ni)
            #pragma unroll
            for (int r = 0; r < 4; ++r) {
                int row = m0 + wr * 64 + mi * 16 + (lane >> 4) * 4 + r;
                int col = n0 + wc * 64 + ni * 16 + (lane & 15);
                float v = acc[mi][ni][r];
                unsigned short h = f2bf(v);
                size_t o = (size_t)row * DM + col;
                Ch[o] = h;
                Cl[o] = f2bf(v - bf2f(h));
            }
}

// ---------------------------------------------------------------------------
// scores_mfma: P = mask(Y.x^T)/32, fp32 out.  3-term split.
// grid (16,16,4) with XCD-chunked swizzle (nwg=1024, cpx=128).
// ---------------------------------------------------------------------------
__global__ __launch_bounds__(256, 2) void scores_mfma(
    const unsigned short* __restrict__ Yh, const unsigned short* __restrict__ Yl,
    const unsigned short* __restrict__ xh, const unsigned short* __restrict__ xl,
    float* __restrict__ P) {
    const int lin = (blockIdx.z * gridDim.y + blockIdx.y) * gridDim.x + blockIdx.x;
    const int logical = (lin & 7) * 128 + (lin >> 3);   // XCD-chunked bijection
    const int jt = logical & 15, t = (logical >> 4) & 15, b = logical >> 8;
    if (jt > t + 1) return;
    const int m0 = t * 128, n0 = jt * 128;
    const size_t qrow0 = (size_t)b * SEQ + m0;
    const size_t krow0 = (size_t)b * SEQ + n0;

    __shared__ short Ah[128 * 64], Al[128 * 64], Bh[128 * 64], Bl[128 * 64];
    const int tid = threadIdx.x, lane = tid & 63, w = tid >> 6;
    const int wr = w >> 1, wc = w & 1;

    f32x4 acc[4][4];
    #pragma unroll
    for (int i = 0; i < 4; ++i)
        #pragma unroll
        for (int j = 0; j < 4; ++j) acc[i][j] = (f32x4){0.f, 0.f, 0.f, 0.f};

    for (int k0 = 0; k0 < DM; k0 += 64) {
        stage_tile(Yh + qrow0 * DM + k0, DM, Ah, tid);
        stage_tile(Yl + qrow0 * DM + k0, DM, Al, tid);
        stage_tile(xh + krow0 * DM + k0, DM, Bh, tid);
        stage_tile(xl + krow0 * DM + k0, DM, Bl, tid);
        __syncthreads();
        #pragma unroll
        for (int ks = 0; ks < 2; ++ks) {
            const int g = ks * 4 + (lane >> 4);
            s16x8 a_h[4], a_l[4], b_h[4], b_l[4];
            #pragma unroll
            for (int mi = 0; mi < 4; ++mi) {
                int r = wr * 64 + mi * 16 + (lane & 15);
                a_h[mi] = lds_frag(Ah, r, g);
                a_l[mi] = lds_frag(Al, r, g);
            }
            #pragma unroll
            for (int ni = 0; ni < 4; ++ni) {
                int r = wc * 64 + ni * 16 + (lane & 15);
                b_h[ni] = lds_frag(Bh, r, g);
                b_l[ni] = lds_frag(Bl, r, g);
            }
            #pragma unroll
            for (int mi = 0; mi < 4; ++mi)
                #pragma unroll
                for (int ni = 0; ni < 4; ++ni) {
                    acc[mi][ni] = MFMA(a_h[mi], b_h[ni], acc[mi][ni]);
                    acc[mi][ni] = MFMA(a_h[mi], b_l[ni], acc[mi][ni]);
                    acc[mi][ni] = MFMA(a_l[mi], b_h[ni], acc[mi][ni]);
                }
        }
        __syncthreads();
    }
    const float scale = 1.0f / 32.0f;
    #pragma unroll
    for (int mi = 0; mi < 4; ++mi)
        #pragma unroll
        for (int ni = 0; ni < 4; ++ni)
            #pragma unroll
            for (int r = 0; r < 4; ++r) {
                int i = m0 + wr * 64 + mi * 16 + (lane >> 4) * 4 + r;
                int j = n0 + wc * 64 + ni * 16 + (lane & 15);
                float v = (j <= i + 1) ? acc[mi][ni][r] * scale : -INFINITY;
                P[((size_t)b * SEQ + i) * SEQ + j] = v;
            }
}

// ---------------------------------------------------------------------------
// softmax_bf16: single-pass row softmax, fp32 logits in -> normalized bf16 out.
// ---------------------------------------------------------------------------
__global__ __launch_bounds__(256) void softmax_bf16(
    const float* __restrict__ P, unsigned short* __restrict__ P2) {
    const int row = blockIdx.x;
    const int b = row >> 11, i = row & (SEQ - 1);
    const int t = i >> 7;
    const int L = min(SEQ, (t + 2) * 128);
    const float* p = P + ((size_t)b * SEQ + i) * SEQ;
    unsigned short* q = P2 + ((size_t)b * SEQ + i) * SEQ;
    const int tid = threadIdx.x;
    __shared__ float red[4];

    float v[8];
    #pragma unroll
    for (int c = 0; c < 8; ++c) {
        int j = c * 256 + tid;
        v[c] = (j < L) ? p[j] : -INFINITY;
    }
    float m = -INFINITY;
    #pragma unroll
    for (int c = 0; c < 8; ++c) m = fmaxf(m, v[c]);
    #pragma unroll
    for (int o = 32; o > 0; o >>= 1) m = fmaxf(m, __shfl_xor(m, o));
    if ((tid & 63) == 0) red[tid >> 6] = m;
    __syncthreads();
    m = fmaxf(fmaxf(red[0], red[1]), fmaxf(red[2], red[3]));
    __syncthreads();

    float s = 0.f;
    #pragma unroll
    for (int c = 0; c < 8; ++c) { v[c] = __expf(v[c] - m); s += v[c]; }
    #pragma unroll
    for (int o = 32; o > 0; o >>= 1) s += __shfl_xor(s, o);
    if ((tid & 63) == 0) red[tid >> 6] = s;
    __syncthreads();
    s = red[0] + red[1] + red[2] + red[3];
    const float inv = 1.f / s;

    #pragma unroll
    for (int c = 0; c < 8; ++c) {
        int j = c * 256 + tid;
        if (j < L) q[j] = f2bf(v[c] * inv);
    }
}

// ---------------------------------------------------------------------------
// pv_mfma: Out = P2(bf16) @ V.  grid (8,16,4) with XCD-chunked swizzle (cpx=64).
// ---------------------------------------------------------------------------
__global__ __launch_bounds__(256, 2) void pv_mfma(
    const unsigned short* __restrict__ P2, const unsigned short* __restrict__ Vt,
    float* __restrict__ Out) {
    const int lin = (blockIdx.z * gridDim.y + blockIdx.y) * gridDim.x + blockIdx.x;
    const int logical = (lin & 7) * 64 + (lin >> 3);    // XCD-chunked bijection
    const int bx = logical & 7, t = (logical >> 3) & 15, b = logical >> 7;
    const int m0 = t * 128, n0 = bx * 128;
    const int jlim = min(SEQ, (t + 2) * 128);

    __shared__ short Pa[128 * 64], Vb[128 * 64];
    const int tid = threadIdx.x, lane = tid & 63, w = tid >> 6;
    const int wr = w >> 1, wc = w & 1;

    f32x4 acc[4][4];
    #pragma unroll
    for (int i = 0; i < 4; ++i)
        #pragma unroll
        for (int j = 0; j < 4; ++j) acc[i][j] = (f32x4){0.f, 0.f, 0.f, 0.f};

    for (int k0 = 0; k0 < jlim; k0 += 64) {
        stage_tile(P2 + ((size_t)b * SEQ + m0) * SEQ + k0, SEQ, Pa, tid);
        stage_tile(Vt + (size_t)n0 * NTOK + (size_t)b * SEQ + k0, NTOK, Vb, tid);
        __syncthreads();
        #pragma unroll
        for (int ks = 0; ks < 2; ++ks) {
            const int g = ks * 4 + (lane >> 4);
            s16x8 a_h[4], b_h[4];
            #pragma unroll
            for (int mi = 0; mi < 4; ++mi)
                a_h[mi] = lds_frag(Pa, wr * 64 + mi * 16 + (lane & 15), g);
            #pragma unroll
            for (int ni = 0; ni < 4; ++ni)
                b_h[ni] = lds_frag(Vb, wc * 64 + ni * 16 + (lane & 15), g);
            #pragma unroll
            for (int mi = 0; mi < 4; ++mi)
                #pragma unroll
                for (int ni = 0; ni < 4; ++ni)
                    acc[mi][ni] = MFMA(a_h[mi], b_h[ni], acc[mi][ni]);
        }
        __syncthreads();
    }
    #pragma unroll
    for (int mi = 0; mi < 4; ++mi)
        #pragma unroll
        for (int ni = 0; ni < 4; ++ni)
            #pragma unroll
            for (int r = 0; r < 4; ++r) {
                int i = m0 + wr * 64 + mi * 16 + (lane >> 4) * 4 + r;
                int col = n0 + wc * 64 + ni * 16 + (lane & 15);
                Out[((size_t)b * SEQ + i) * DM + col] = acc[mi][ni][r];
            }
}

// ---------------------------------------------------------------------------
extern "C" void kernel_launch(void* const* d_in, const int* in_sizes, int n_in,
                              void* d_out, int out_size, void* d_ws, size_t ws_size,
                              hipStream_t stream) {
    const float* x  = (const float*)d_in[0];
    const float* Wq = (const float*)d_in[1];
    const float* Wk = (const float*)d_in[2];
    const float* Wv = (const float*)d_in[3];

    // Workspace layout (bytes):
    //   [0   , 2NE)  : Vt bf16 [n=1024][tok=8192]          (live till pv)
    //   [2NE , 6NE)  : xh, xl bf16 (live till scores) -> P2 bf16 (softmax..pv)
    //   [6NE , 14NE) : P fp32; W-splits + M' + Wvt + Mslabs live inside BEFORE scores
    char* ws = (char*)d_ws;
    unsigned short* Vt = (unsigned short*)ws;               // NE elems
    unsigned short* xh = (unsigned short*)(ws + 2 * NE);    // NE
    unsigned short* xl = (unsigned short*)(ws + 4 * NE);    // NE
    float* P = (float*)(ws + 6 * NE);                       // 8*NE bytes
    unsigned short* P2 = (unsigned short*)(ws + 2 * NE);    // over xh/xl (4NE B)
    // scratch inside P's byte range (all dead before scores writes P):
    unsigned short* Wqh = (unsigned short*)(ws + 6 * NE);   // WN each
    unsigned short* Wql = Wqh + WN;
    unsigned short* Wkh = Wql + WN;
    unsigned short* Wkl = Wkh + WN;
    unsigned short* Mh  = Wkl + WN;    // M' = Wk.Wq^T hi
    unsigned short* Ml  = Mh + WN;     // M' lo
    unsigned short* Wvt = Ml + WN;     // Wv^T hi
    float* Mslab = (float*)(ws + 6 * NE + 7 * WN * 2);      // 8*WN fp32 = 32 MB
    // Y splits use d_out as scratch (dead after scores; overwritten by Out):
    unsigned short* Yh = (unsigned short*)d_out;
    unsigned short* Yl = Yh + NE;

    split_x<<<2048, 256, 0, stream>>>(x, xh, xl);
    {
        dim3 g(16, 16, 3);
        split_w<<<g, 256, 0, stream>>>(Wq, Wk, Wv, Wqh, Wql, Wkh, Wkl, Wvt);
    }
    // M' split-K (512 blk) fused with Vt GEMM (512 blk)
    mvt_fused<<<1024, 256, 0, stream>>>(Wkh, Wkl, Wqh, Wql, Mslab, Wvt, xh, Vt);
    // reduce slabs -> M' hi/lo
    mreduce<<<1024, 256, 0, stream>>>(Mslab, Mh, Ml);
    {   // Y[i][e] = sum_d x[i,d] M'[e,d]
        dim3 g(NTOK / 128, DM / 128);
        gemm3_split<<<g, 256, 0, stream>>>(xh, xl, Mh, Ml, Yh, Yl);
    }
    {
        dim3 g(16, 16, 4);
        scores_mfma<<<g, 256, 0, stream>>>(Yh, Yl, xh, xl, P);
    }
    softmax_bf16<<<BATCH * SEQ, 256, 0, stream>>>(P, P2);
    {
        dim3 g(8, 16, 4);
        pv_mfma<<<g, 256, 0, stream>>>(P2, Vt, (float*)d_out);
    }
}